// Round 9
// baseline (1499.045 us; speedup 1.0000x reference)
//
#include <hip/hip_runtime.h>

#define EPS 1e-5f
#define SLOPE 0.01f

typedef float f32x2 __attribute__((ext_vector_type(2)));

// ===========================================================================
// Scatter conv, 8-edge groups, 1-deep register prefetch (R5/R7 verified
// structure) + three instruction-count cuts:
//  - packed fp32 FMA via vector arithmetic (clang contracts f32x2 mul+add
//    to v_pk_fma_f32 where supported; falls back to 2x v_fma_f32 safely)
//  - W transposed in LDS (Wt[i/4][c][4]): one conflict-free b128 per 4 w's
//  - vectorized gather: float4 global load + ds_write_b128 per lane
// ===========================================================================
template<int CHUNKS>
__global__ __launch_bounds__(256) void conv_scatter8(
    const float* __restrict__ x, const float* __restrict__ W,
    const int* __restrict__ src, const int* __restrict__ dst,
    float* __restrict__ acc, int E)
{
    constexpr int CIN = CHUNKS * 64;
    constexpr int LPE = CIN / 4;        // lanes per edge row (16B each)
    constexpr int EPP = 64 / LPE;       // edges per gather pass
    constexpr int NP  = 8 / EPP;        // passes per 8-edge group
    __shared__ float Wt[CIN * 64];      // transposed: [(i>>2)][c][i&3]
    __shared__ float xl[4][8 * CIN];
    const int k   = blockIdx.y;
    const int tid = threadIdx.x;
    const int w   = tid >> 6;
    const int c   = tid & 63;

    // stage W[k] transposed into LDS (one-time)
    const float* Wk = W + (size_t)k * (CIN * 64);
    for (int i0 = tid * 4; i0 < CIN * 64; i0 += 1024) {
        const float4 v = *(const float4*)&Wk[i0];  // W[i][c0..c0+3]
        const int i  = i0 >> 6;
        const int c0 = i0 & 63;
        const int b  = (i >> 2) * 256 + (i & 3);
        Wt[b + (c0 + 0) * 4] = v.x;
        Wt[b + (c0 + 1) * 4] = v.y;
        Wt[b + (c0 + 2) * 4] = v.z;
        Wt[b + (c0 + 3) * 4] = v.w;
    }
    __syncthreads();

    const int* srcK = src + (size_t)k * E;
    const int* dstK = dst + (size_t)k * E;
    float* xw = xl[w];
    const int stride = gridDim.x * 32;
    const int last = E - 1;
    const int epl = c / LPE;               // this lane's edge within a pass
    const int fo  = (c & (LPE - 1)) * 4;   // float offset within edge row

    int e0 = blockIdx.x * 32 + w * 8;
    if (e0 >= E) return;

    int    qs[NP];
    float4 gv[NP];
    #pragma unroll
    for (int p = 0; p < NP; ++p) {
        qs[p] = srcK[min(e0 + p * EPP + epl, last)];
        gv[p] = *(const float4*)&x[(size_t)qs[p] * CIN + fo];
    }

    while (e0 < E) {
        const int ne = E - e0;
        int d[8];
        #pragma unroll
        for (int j = 0; j < 8; ++j) d[j] = dstK[min(e0 + j, last)];
        // commit current gather group to LDS (b128, conflict-free)
        #pragma unroll
        for (int p = 0; p < NP; ++p)
            *(float4*)&xw[(p * EPP + epl) * CIN + fo] = gv[p];
        const int en = e0 + stride;
        if (en < E) {   // issue next group's loads before the FMA block
            #pragma unroll
            for (int p = 0; p < NP; ++p) {
                qs[p] = srcK[min(en + p * EPP + epl, last)];
                gv[p] = *(const float4*)&x[(size_t)qs[p] * CIN + fo];
            }
        }
        __builtin_amdgcn_wave_barrier();

        f32x2 a2[8];
        #pragma unroll
        for (int j = 0; j < 8; ++j) a2[j] = (f32x2){0.f, 0.f};
        #pragma unroll 4
        for (int i = 0; i < CIN; i += 4) {
            const float4 wq = *(const float4*)&Wt[(i >> 2) * 256 + c * 4];
            const f32x2 wlo = ((const f32x2*)&wq)[0];
            const f32x2 whi = ((const f32x2*)&wq)[1];
            #pragma unroll
            for (int j = 0; j < 8; ++j) {
                const float4 xv = *(const float4*)&xw[j * CIN + i];
                a2[j] = ((const f32x2*)&xv)[0] * wlo + a2[j];
                a2[j] = ((const f32x2*)&xv)[1] * whi + a2[j];
            }
        }
        __builtin_amdgcn_wave_barrier();

        #pragma unroll
        for (int j = 0; j < 8; ++j)
            if (j < ne) atomicAdd(&acc[(size_t)d[j] * 64 + c], a2[j].x + a2[j].y);
        e0 = en;
    }
}

// ---------------------------------------------------------------------------
// Cin=1 conv (baseline-verified): out[dst,:64] += s1[src] * W_up[k,0,:].
// ---------------------------------------------------------------------------
__global__ __launch_bounds__(256) void conv_up_kernel(
    const float* __restrict__ s1, const float* __restrict__ Wup,
    const int* __restrict__ gsrc, const int* __restrict__ sdst,
    float* __restrict__ out, int E)
{
    const int k = blockIdx.y;
    const int c = threadIdx.x & 63;
    const int w = threadIdx.x >> 6;
    const float wv = Wup[k * 64 + c];
    for (int e = blockIdx.x * 4 + w; e < E; e += gridDim.x * 4) {
        const float val = s1[gsrc[(size_t)k * E + e]];
        const int   di  = sdst[(size_t)k * E + e];
        atomicAdd(&out[(size_t)di * 64 + c], val * wv);
    }
}

// ---------------------------------------------------------------------------
// Cout=1 conv: acc1[dst] += dot(s[src,:64], W_sum[k,:,0]). Thread-per-edge.
// ---------------------------------------------------------------------------
__global__ __launch_bounds__(256) void conv_sum_kernel(
    const float* __restrict__ s, const float* __restrict__ Wsum,
    const int* __restrict__ src, const int* __restrict__ dst,
    float* __restrict__ acc1, int E)
{
    const int k = blockIdx.y;
    __shared__ float Wl[64];
    if (threadIdx.x < 64) Wl[threadIdx.x] = Wsum[k * 64 + threadIdx.x];
    __syncthreads();
    for (int e = blockIdx.x * 256 + threadIdx.x; e < E; e += gridDim.x * 256) {
        const int si = src[(size_t)k * E + e];
        const float4* row = (const float4*)(s + (size_t)si * 64);
        float acc = 0.f;
        #pragma unroll
        for (int q = 0; q < 16; ++q) {
            const float4 v = row[q];
            acc = fmaf(v.x, Wl[q * 4 + 0], acc);
            acc = fmaf(v.y, Wl[q * 4 + 1], acc);
            acc = fmaf(v.z, Wl[q * 4 + 2], acc);
            acc = fmaf(v.w, Wl[q * 4 + 3], acc);
        }
        atomicAdd(&acc1[dst[(size_t)k * E + e]], acc);
    }
}

// ---------------------------------------------------------------------------
// Per-channel (C=64) sum/sumsq (baseline-verified atomic form).
// ---------------------------------------------------------------------------
__global__ __launch_bounds__(256) void stats64(
    const float* __restrict__ x, int N, float* __restrict__ st)
{
    const int c  = threadIdx.x & 63;
    const int rg = threadIdx.x >> 6;
    float s = 0.f, q = 0.f;
    for (int r = blockIdx.x * 4 + rg; r < N; r += gridDim.x * 4) {
        const float v = x[(size_t)r * 64 + c];
        s += v;
        q = fmaf(v, v, q);
    }
    __shared__ float ls[256], lq[256];
    ls[threadIdx.x] = s; lq[threadIdx.x] = q;
    __syncthreads();
    if (threadIdx.x < 64) {
        s = ls[c] + ls[64 + c] + ls[128 + c] + ls[192 + c];
        q = lq[c] + lq[64 + c] + lq[128 + c] + lq[192 + c];
        atomicAdd(&st[c], s);
        atomicAdd(&st[64 + c], q);
    }
}

__global__ __launch_bounds__(256) void stats1(
    const float* __restrict__ x, int N, float* __restrict__ st)
{
    float s = 0.f, q = 0.f;
    for (int i = blockIdx.x * 256 + threadIdx.x; i < N; i += gridDim.x * 256) {
        const float v = x[i];
        s += v;
        q = fmaf(v, v, q);
    }
    __shared__ float ls[256], lq[256];
    ls[threadIdx.x] = s; lq[threadIdx.x] = q;
    __syncthreads();
    for (int off = 128; off > 0; off >>= 1) {
        if (threadIdx.x < off) {
            ls[threadIdx.x] += ls[threadIdx.x + off];
            lq[threadIdx.x] += lq[threadIdx.x + off];
        }
        __syncthreads();
    }
    if (threadIdx.x == 0) { atomicAdd(&st[0], ls[0]); atomicAdd(&st[1], lq[0]); }
}

// ---------------------------------------------------------------------------
// In-place BN + activation (ACT 0=LeakyReLU, 1=sigmoid), optional += add.
// ---------------------------------------------------------------------------
template<int ACT>
__global__ __launch_bounds__(256) void apply_bn(
    float* __restrict__ x, const float* __restrict__ st, int N, float invN,
    const float* __restrict__ gam, const float* __restrict__ bet,
    const float* __restrict__ add)
{
    __shared__ float sc[64], sh[64];
    if (threadIdx.x < 64) {
        const int c = threadIdx.x;
        const float m = st[c] * invN;
        const float v = st[64 + c] * invN - m * m;
        const float s = rsqrtf(v + EPS) * gam[c];
        sc[c] = s;
        sh[c] = bet[c] - m * s;
    }
    __syncthreads();
    const size_t n = (size_t)N * 64;
    for (size_t i = (size_t)blockIdx.x * 256 + threadIdx.x; i < n;
         i += (size_t)gridDim.x * 256) {
        const int c = (int)(i & 63);
        float y = fmaf(x[i], sc[c], sh[c]);
        if (ACT == 0) y = (y >= 0.f) ? y : SLOPE * y;
        else          y = 1.f / (1.f + __expf(-y));
        if (add) y += add[i];
        x[i] = y;
    }
}

__global__ __launch_bounds__(256) void apply_bn1(
    float* __restrict__ x, const float* __restrict__ st, int N, float invN,
    const float* __restrict__ gam, const float* __restrict__ bet)
{
    const float m  = st[0] * invN;
    const float v  = st[1] * invN - m * m;
    const float s  = rsqrtf(v + EPS) * gam[0];
    const float sh = bet[0] - m * s;
    for (int i = blockIdx.x * 256 + threadIdx.x; i < N; i += gridDim.x * 256) {
        const float y = fmaf(x[i], s, sh);
        x[i] = (y >= 0.f) ? y : SLOPE * y;
    }
}

// ---------------------------------------------------------------------------
extern "C" void kernel_launch(void* const* d_in, const int* in_sizes, int n_in,
                              void* d_out, int out_size, void* d_ws, size_t ws_size,
                              hipStream_t stream)
{
    const float* gate     = (const float*)d_in[0];
    const float* shortcut = (const float*)d_in[1];
    const int*   src_down = (const int*)d_in[2];
    const int*   dst_down = (const int*)d_in[3];
    const int*   src_g    = (const int*)d_in[4];
    const int*   dst_g    = (const int*)d_in[5];
    const float* W_sc     = (const float*)d_in[6];
    const float* W_g      = (const float*)d_in[8];
    const float* W_gu     = (const float*)d_in[10];
    const float* W_sum    = (const float*)d_in[12];
    const float* W_up     = (const float*)d_in[13];
    const float* gam_sc   = (const float*)d_in[15];
    const float* bet_sc   = (const float*)d_in[16];
    const float* gam_g    = (const float*)d_in[17];
    const float* bet_g    = (const float*)d_in[18];
    const float* gam_gu   = (const float*)d_in[19];
    const float* bet_gu   = (const float*)d_in[20];
    const float* gam_sum  = (const float*)d_in[21];
    const float* bet_sum  = (const float*)d_in[22];
    const float* gam_up   = (const float*)d_in[23];
    const float* bet_up   = (const float*)d_in[24];

    const int K   = 27;
    const int Nc  = in_sizes[0] / 128;   // 60000
    const int Nf  = in_sizes[1] / 64;    // 200000
    const int Ekd = in_sizes[2] / K;     // 40000
    const int Ekg = in_sizes[4] / K;     // 25000

    float* A  = (float*)d_ws;            // acc_theta -> theta
    float* B  = A + (size_t)Nc * 64;     // acc_phi   -> phi
    float* C  = B + (size_t)Nc * 64;     // acc_phi2  -> s
    float* D  = C + (size_t)Nc * 64;     // acc_s1    -> s1
    float* ST = D + Nc;                  // stats: 640 floats
    const size_t zeroBytes = ((size_t)Nc * 64 * 3 + (size_t)Nc + 640) * sizeof(float);
    hipMemsetAsync(d_ws, 0, zeroBytes, stream);
    hipMemsetAsync(d_out, 0, (size_t)out_size * sizeof(float), stream);
    float* out = (float*)d_out;

    const dim3 blk(256);

    // theta = leaky(bn(sconv(shortcut, W_sc, src_down->dst_down)))
    conv_scatter8<1><<<dim3(64, K), blk, 0, stream>>>(shortcut, W_sc, src_down, dst_down, A, Ekd);
    // phi_raw = sconv(gate, W_g, src_g->dst_g)
    conv_scatter8<2><<<dim3(64, K), blk, 0, stream>>>(gate, W_g, src_g, dst_g, B, Ekg);

    stats64<<<256, blk, 0, stream>>>(A, Nc, ST + 0);
    stats64<<<256, blk, 0, stream>>>(B, Nc, ST + 128);
    apply_bn<0><<<1024, blk, 0, stream>>>(A, ST + 0,   Nc, 1.0f / Nc, gam_sc, bet_sc, nullptr);
    apply_bn<0><<<1024, blk, 0, stream>>>(B, ST + 128, Nc, 1.0f / Nc, gam_g,  bet_g,  nullptr);

    // phi = leaky(bn(sconv(phi, W_gu, dst_g->src_g)))  (transposed index pairs)
    conv_scatter8<1><<<dim3(64, K), blk, 0, stream>>>(B, W_gu, dst_g, src_g, C, Ekg);
    stats64<<<256, blk, 0, stream>>>(C, Nc, ST + 256);
    // s = leaky(bn(C)) + theta
    apply_bn<0><<<1024, blk, 0, stream>>>(C, ST + 256, Nc, 1.0f / Nc, gam_gu, bet_gu, A);

    // s1 = leaky(bn(sconv(s, W_sum, src_g->dst_g)))   (Cout = 1)
    conv_sum_kernel<<<dim3(32, K), blk, 0, stream>>>(C, W_sum, src_g, dst_g, D, Ekg);
    stats1<<<256, blk, 0, stream>>>(D, Nc, ST + 384);
    apply_bn1<<<256, blk, 0, stream>>>(D, ST + 384, Nc, 1.0f / Nc, gam_sum, bet_sum);

    // out = sigmoid(bn(sconv(s1, W_up, dst_down->src_down)))  (Cin = 1, fine res)
    conv_up_kernel<<<dim3(64, K), blk, 0, stream>>>(D, W_up, dst_down, src_down, out, Ekd);
    stats64<<<512, blk, 0, stream>>>(out, Nf, ST + 512);
    apply_bn<1><<<2048, blk, 0, stream>>>(out, ST + 512, Nf, 1.0f / Nf, gam_up, bet_up, nullptr);
}

// Round 10
// 1447.756 us; speedup vs baseline: 1.0354x; 1.0354x over previous
//
#include <hip/hip_runtime.h>

#define EPS 1e-5f
#define SLOPE 0.01f

typedef float f32x2 __attribute__((ext_vector_type(2)));

// ===========================================================================
// Scatter conv + 8-edge groups + 1-deep register prefetch (R7-verified
// memory structure: W broadcast-friendly stride-4B reads, scalar gather,
// conflict-free LDS). ONLY change vs R7: the inner FMA block accumulates
// in f32x2 so clang can contract to v_pk_fma_f32 (2 channel-FMAs/instr).
// All LDS/global access patterns are byte-identical to R7.
// ===========================================================================
template<int CHUNKS>
__global__ __launch_bounds__(256) void conv_scatter8(
    const float* __restrict__ x, const float* __restrict__ W,
    const int* __restrict__ src, const int* __restrict__ dst,
    float* __restrict__ acc, int E)
{
    constexpr int CIN = CHUNKS * 64;
    __shared__ float Wl[CIN * 64];
    __shared__ float xl[4][8 * CIN];
    const int k   = blockIdx.y;
    const int tid = threadIdx.x;
    const int w   = tid >> 6;
    const int c   = tid & 63;

    const float* Wk = W + (size_t)k * (CIN * 64);
    for (int i = tid * 4; i < CIN * 64; i += 1024)
        *(float4*)&Wl[i] = *(const float4*)&Wk[i];
    __syncthreads();

    const int* srcK = src + (size_t)k * E;
    const int* dstK = dst + (size_t)k * E;
    float* xw = xl[w];
    const int stride = gridDim.x * 32;
    const int last = E - 1;

    int e0 = blockIdx.x * 32 + w * 8;
    if (e0 >= E) return;

    int   q[8];
    float g[8][CHUNKS];
    #pragma unroll
    for (int j = 0; j < 8; ++j) q[j] = srcK[min(e0 + j, last)];
    #pragma unroll
    for (int j = 0; j < 8; ++j)
        #pragma unroll
        for (int h = 0; h < CHUNKS; ++h)
            g[j][h] = x[(size_t)q[j] * CIN + h * 64 + c];

    while (e0 < E) {
        const int ne = E - e0;
        int d[8];
        #pragma unroll
        for (int j = 0; j < 8; ++j) d[j] = dstK[min(e0 + j, last)];
        // commit current gather group to LDS (stride-1 per lane: conflict-free)
        #pragma unroll
        for (int j = 0; j < 8; ++j)
            #pragma unroll
            for (int h = 0; h < CHUNKS; ++h)
                xw[j * CIN + h * 64 + c] = g[j][h];
        const int en = e0 + stride;
        if (en < E) {   // issue next group's loads before the FMA block
            #pragma unroll
            for (int j = 0; j < 8; ++j) q[j] = srcK[min(en + j, last)];
            #pragma unroll
            for (int j = 0; j < 8; ++j)
                #pragma unroll
                for (int h = 0; h < CHUNKS; ++h)
                    g[j][h] = x[(size_t)q[j] * CIN + h * 64 + c];
        }
        __builtin_amdgcn_wave_barrier();

        f32x2 a2[8];
        #pragma unroll
        for (int j = 0; j < 8; ++j) a2[j] = (f32x2){0.f, 0.f};
        #pragma unroll 4
        for (int i = 0; i < CIN; i += 4) {
            // same stride-4B scalar reads as R7 (2 lanes/bank = free)
            const float w0 = Wl[(i + 0) * 64 + c];
            const float w1 = Wl[(i + 1) * 64 + c];
            const float w2 = Wl[(i + 2) * 64 + c];
            const float w3 = Wl[(i + 3) * 64 + c];
            const f32x2 wA = {w0, w1};
            const f32x2 wB = {w2, w3};
            #pragma unroll
            for (int j = 0; j < 8; ++j) {
                const float4 xv = *(const float4*)&xw[j * CIN + i];  // broadcast
                a2[j] = ((const f32x2*)&xv)[0] * wA + a2[j];
                a2[j] = ((const f32x2*)&xv)[1] * wB + a2[j];
            }
        }
        __builtin_amdgcn_wave_barrier();

        #pragma unroll
        for (int j = 0; j < 8; ++j)
            if (j < ne) atomicAdd(&acc[(size_t)d[j] * 64 + c], a2[j].x + a2[j].y);
        e0 = en;
    }
}

// ---------------------------------------------------------------------------
// Cin=1 conv (baseline-verified): out[dst,:64] += s1[src] * W_up[k,0,:].
// ---------------------------------------------------------------------------
__global__ __launch_bounds__(256) void conv_up_kernel(
    const float* __restrict__ s1, const float* __restrict__ Wup,
    const int* __restrict__ gsrc, const int* __restrict__ sdst,
    float* __restrict__ out, int E)
{
    const int k = blockIdx.y;
    const int c = threadIdx.x & 63;
    const int w = threadIdx.x >> 6;
    const float wv = Wup[k * 64 + c];
    for (int e = blockIdx.x * 4 + w; e < E; e += gridDim.x * 4) {
        const float val = s1[gsrc[(size_t)k * E + e]];
        const int   di  = sdst[(size_t)k * E + e];
        atomicAdd(&out[(size_t)di * 64 + c], val * wv);
    }
}

// ---------------------------------------------------------------------------
// Cout=1 conv: acc1[dst] += dot(s[src,:64], W_sum[k,:,0]). Thread-per-edge.
// ---------------------------------------------------------------------------
__global__ __launch_bounds__(256) void conv_sum_kernel(
    const float* __restrict__ s, const float* __restrict__ Wsum,
    const int* __restrict__ src, const int* __restrict__ dst,
    float* __restrict__ acc1, int E)
{
    const int k = blockIdx.y;
    __shared__ float Wl[64];
    if (threadIdx.x < 64) Wl[threadIdx.x] = Wsum[k * 64 + threadIdx.x];
    __syncthreads();
    for (int e = blockIdx.x * 256 + threadIdx.x; e < E; e += gridDim.x * 256) {
        const int si = src[(size_t)k * E + e];
        const float4* row = (const float4*)(s + (size_t)si * 64);
        float acc = 0.f;
        #pragma unroll
        for (int q = 0; q < 16; ++q) {
            const float4 v = row[q];
            acc = fmaf(v.x, Wl[q * 4 + 0], acc);
            acc = fmaf(v.y, Wl[q * 4 + 1], acc);
            acc = fmaf(v.z, Wl[q * 4 + 2], acc);
            acc = fmaf(v.w, Wl[q * 4 + 3], acc);
        }
        atomicAdd(&acc1[dst[(size_t)k * E + e]], acc);
    }
}

// ---------------------------------------------------------------------------
// Per-channel (C=64) sum/sumsq (baseline-verified atomic form).
// ---------------------------------------------------------------------------
__global__ __launch_bounds__(256) void stats64(
    const float* __restrict__ x, int N, float* __restrict__ st)
{
    const int c  = threadIdx.x & 63;
    const int rg = threadIdx.x >> 6;
    float s = 0.f, q = 0.f;
    for (int r = blockIdx.x * 4 + rg; r < N; r += gridDim.x * 4) {
        const float v = x[(size_t)r * 64 + c];
        s += v;
        q = fmaf(v, v, q);
    }
    __shared__ float ls[256], lq[256];
    ls[threadIdx.x] = s; lq[threadIdx.x] = q;
    __syncthreads();
    if (threadIdx.x < 64) {
        s = ls[c] + ls[64 + c] + ls[128 + c] + ls[192 + c];
        q = lq[c] + lq[64 + c] + lq[128 + c] + lq[192 + c];
        atomicAdd(&st[c], s);
        atomicAdd(&st[64 + c], q);
    }
}

__global__ __launch_bounds__(256) void stats1(
    const float* __restrict__ x, int N, float* __restrict__ st)
{
    float s = 0.f, q = 0.f;
    for (int i = blockIdx.x * 256 + threadIdx.x; i < N; i += gridDim.x * 256) {
        const float v = x[i];
        s += v;
        q = fmaf(v, v, q);
    }
    __shared__ float ls[256], lq[256];
    ls[threadIdx.x] = s; lq[threadIdx.x] = q;
    __syncthreads();
    for (int off = 128; off > 0; off >>= 1) {
        if (threadIdx.x < off) {
            ls[threadIdx.x] += ls[threadIdx.x + off];
            lq[threadIdx.x] += lq[threadIdx.x + off];
        }
        __syncthreads();
    }
    if (threadIdx.x == 0) { atomicAdd(&st[0], ls[0]); atomicAdd(&st[1], lq[0]); }
}

// ---------------------------------------------------------------------------
// In-place BN + activation (ACT 0=LeakyReLU, 1=sigmoid), optional += add.
// ---------------------------------------------------------------------------
template<int ACT>
__global__ __launch_bounds__(256) void apply_bn(
    float* __restrict__ x, const float* __restrict__ st, int N, float invN,
    const float* __restrict__ gam, const float* __restrict__ bet,
    const float* __restrict__ add)
{
    __shared__ float sc[64], sh[64];
    if (threadIdx.x < 64) {
        const int c = threadIdx.x;
        const float m = st[c] * invN;
        const float v = st[64 + c] * invN - m * m;
        const float s = rsqrtf(v + EPS) * gam[c];
        sc[c] = s;
        sh[c] = bet[c] - m * s;
    }
    __syncthreads();
    const size_t n = (size_t)N * 64;
    for (size_t i = (size_t)blockIdx.x * 256 + threadIdx.x; i < n;
         i += (size_t)gridDim.x * 256) {
        const int c = (int)(i & 63);
        float y = fmaf(x[i], sc[c], sh[c]);
        if (ACT == 0) y = (y >= 0.f) ? y : SLOPE * y;
        else          y = 1.f / (1.f + __expf(-y));
        if (add) y += add[i];
        x[i] = y;
    }
}

__global__ __launch_bounds__(256) void apply_bn1(
    float* __restrict__ x, const float* __restrict__ st, int N, float invN,
    const float* __restrict__ gam, const float* __restrict__ bet)
{
    const float m  = st[0] * invN;
    const float v  = st[1] * invN - m * m;
    const float s  = rsqrtf(v + EPS) * gam[0];
    const float sh = bet[0] - m * s;
    for (int i = blockIdx.x * 256 + threadIdx.x; i < N; i += gridDim.x * 256) {
        const float y = fmaf(x[i], s, sh);
        x[i] = (y >= 0.f) ? y : SLOPE * y;
    }
}

// ---------------------------------------------------------------------------
extern "C" void kernel_launch(void* const* d_in, const int* in_sizes, int n_in,
                              void* d_out, int out_size, void* d_ws, size_t ws_size,
                              hipStream_t stream)
{
    const float* gate     = (const float*)d_in[0];
    const float* shortcut = (const float*)d_in[1];
    const int*   src_down = (const int*)d_in[2];
    const int*   dst_down = (const int*)d_in[3];
    const int*   src_g    = (const int*)d_in[4];
    const int*   dst_g    = (const int*)d_in[5];
    const float* W_sc     = (const float*)d_in[6];
    const float* W_g      = (const float*)d_in[8];
    const float* W_gu     = (const float*)d_in[10];
    const float* W_sum    = (const float*)d_in[12];
    const float* W_up     = (const float*)d_in[13];
    const float* gam_sc   = (const float*)d_in[15];
    const float* bet_sc   = (const float*)d_in[16];
    const float* gam_g    = (const float*)d_in[17];
    const float* bet_g    = (const float*)d_in[18];
    const float* gam_gu   = (const float*)d_in[19];
    const float* bet_gu   = (const float*)d_in[20];
    const float* gam_sum  = (const float*)d_in[21];
    const float* bet_sum  = (const float*)d_in[22];
    const float* gam_up   = (const float*)d_in[23];
    const float* bet_up   = (const float*)d_in[24];

    const int K   = 27;
    const int Nc  = in_sizes[0] / 128;   // 60000
    const int Nf  = in_sizes[1] / 64;    // 200000
    const int Ekd = in_sizes[2] / K;     // 40000
    const int Ekg = in_sizes[4] / K;     // 25000

    float* A  = (float*)d_ws;            // acc_theta -> theta
    float* B  = A + (size_t)Nc * 64;     // acc_phi   -> phi
    float* C  = B + (size_t)Nc * 64;     // acc_phi2  -> s
    float* D  = C + (size_t)Nc * 64;     // acc_s1    -> s1
    float* ST = D + Nc;                  // stats: 640 floats
    const size_t zeroBytes = ((size_t)Nc * 64 * 3 + (size_t)Nc + 640) * sizeof(float);
    hipMemsetAsync(d_ws, 0, zeroBytes, stream);
    hipMemsetAsync(d_out, 0, (size_t)out_size * sizeof(float), stream);
    float* out = (float*)d_out;

    const dim3 blk(256);

    // theta = leaky(bn(sconv(shortcut, W_sc, src_down->dst_down)))
    conv_scatter8<1><<<dim3(64, K), blk, 0, stream>>>(shortcut, W_sc, src_down, dst_down, A, Ekd);
    // phi_raw = sconv(gate, W_g, src_g->dst_g)
    conv_scatter8<2><<<dim3(64, K), blk, 0, stream>>>(gate, W_g, src_g, dst_g, B, Ekg);

    stats64<<<256, blk, 0, stream>>>(A, Nc, ST + 0);
    stats64<<<256, blk, 0, stream>>>(B, Nc, ST + 128);
    apply_bn<0><<<1024, blk, 0, stream>>>(A, ST + 0,   Nc, 1.0f / Nc, gam_sc, bet_sc, nullptr);
    apply_bn<0><<<1024, blk, 0, stream>>>(B, ST + 128, Nc, 1.0f / Nc, gam_g,  bet_g,  nullptr);

    // phi = leaky(bn(sconv(phi, W_gu, dst_g->src_g)))  (transposed index pairs)
    conv_scatter8<1><<<dim3(64, K), blk, 0, stream>>>(B, W_gu, dst_g, src_g, C, Ekg);
    stats64<<<256, blk, 0, stream>>>(C, Nc, ST + 256);
    // s = leaky(bn(C)) + theta
    apply_bn<0><<<1024, blk, 0, stream>>>(C, ST + 256, Nc, 1.0f / Nc, gam_gu, bet_gu, A);

    // s1 = leaky(bn(sconv(s, W_sum, src_g->dst_g)))   (Cout = 1)
    conv_sum_kernel<<<dim3(32, K), blk, 0, stream>>>(C, W_sum, src_g, dst_g, D, Ekg);
    stats1<<<256, blk, 0, stream>>>(D, Nc, ST + 384);
    apply_bn1<<<256, blk, 0, stream>>>(D, ST + 384, Nc, 1.0f / Nc, gam_sum, bet_sum);

    // out = sigmoid(bn(sconv(s1, W_up, dst_down->src_down)))  (Cin = 1, fine res)
    conv_up_kernel<<<dim3(64, K), blk, 0, stream>>>(D, W_up, dst_down, src_down, out, Ekd);
    stats64<<<512, blk, 0, stream>>>(out, Nf, ST + 512);
    apply_bn<1><<<2048, blk, 0, stream>>>(out, ST + 512, Nf, 1.0f / Nf, gam_up, bet_up, nullptr);
}

// Round 12
// 1327.789 us; speedup vs baseline: 1.1290x; 1.0904x over previous
//
#include <hip/hip_runtime.h>

#define EPS 1e-5f
#define SLOPE 0.01f

// ===========================================================================
// Scatter conv + 8-edge groups + 1-deep register prefetch (R7-verified
// memory patterns and scalar-fmaf inner loop). x-stage LDS buffer is one
// 64-channel chunk (8 KB) regardless of CIN; CIN=128 runs the group as two
// chunk passes. LDS: CIN=64 24 KB (6 blocks/CU), CIN=128 40 KB (4 blocks/CU).
// ===========================================================================
template<int CHUNKS>
__global__ __launch_bounds__(256) void conv_scatter8(
    const float* __restrict__ x, const float* __restrict__ W,
    const int* __restrict__ src, const int* __restrict__ dst,
    float* __restrict__ acc, int E)
{
    constexpr int CIN = CHUNKS * 64;
    __shared__ float Wl[CIN * 64];      // 16/32 KB
    __shared__ float xl[4][8 * 64];     // 8 KB: per-wave 8 edges x 64-ch chunk
    const int k   = blockIdx.y;
    const int tid = threadIdx.x;
    const int w   = tid >> 6;
    const int c   = tid & 63;

    const float* Wk = W + (size_t)k * (CIN * 64);
    for (int i = tid * 4; i < CIN * 64; i += 1024)
        *(float4*)&Wl[i] = *(const float4*)&Wk[i];
    __syncthreads();

    const int* srcK = src + (size_t)k * E;
    const int* dstK = dst + (size_t)k * E;
    float* xw = xl[w];
    const int stride = gridDim.x * 32;
    const int last = E - 1;

    int e0 = blockIdx.x * 32 + w * 8;
    if (e0 >= E) return;

    int   q[8];
    float g[8][CHUNKS];
    #pragma unroll
    for (int j = 0; j < 8; ++j) q[j] = srcK[min(e0 + j, last)];
    #pragma unroll
    for (int j = 0; j < 8; ++j)
        #pragma unroll
        for (int h = 0; h < CHUNKS; ++h)
            g[j][h] = x[(size_t)q[j] * CIN + h * 64 + c];

    while (e0 < E) {
        const int ne = E - e0;
        int d[8];
        #pragma unroll
        for (int j = 0; j < 8; ++j) d[j] = dstK[min(e0 + j, last)];
        const int en = e0 + stride;

        float a[8] = {0.f, 0.f, 0.f, 0.f, 0.f, 0.f, 0.f, 0.f};
        #pragma unroll
        for (int h = 0; h < CHUNKS; ++h) {
            // commit chunk h of the current group to LDS (stride-1: conflict-free)
            #pragma unroll
            for (int j = 0; j < 8; ++j)
                xw[j * 64 + c] = g[j][h];
            // after the LAST commit, g is dead: issue next group's loads so
            // HBM latency hides under the remaining FMA work
            if (h == CHUNKS - 1 && en < E) {
                #pragma unroll
                for (int j = 0; j < 8; ++j) q[j] = srcK[min(en + j, last)];
                #pragma unroll
                for (int j = 0; j < 8; ++j)
                    #pragma unroll
                    for (int h2 = 0; h2 < CHUNKS; ++h2)
                        g[j][h2] = x[(size_t)q[j] * CIN + h2 * 64 + c];
            }
            __builtin_amdgcn_wave_barrier();

            #pragma unroll 4
            for (int i = 0; i < 64; i += 4) {
                const float w0 = Wl[(h * 64 + i + 0) * 64 + c];
                const float w1 = Wl[(h * 64 + i + 1) * 64 + c];
                const float w2 = Wl[(h * 64 + i + 2) * 64 + c];
                const float w3 = Wl[(h * 64 + i + 3) * 64 + c];
                #pragma unroll
                for (int j = 0; j < 8; ++j) {
                    const float4 xv = *(const float4*)&xw[j * 64 + i];  // broadcast
                    a[j] = fmaf(xv.w, w3, fmaf(xv.z, w2, fmaf(xv.y, w1, fmaf(xv.x, w0, a[j]))));
                }
            }
            __builtin_amdgcn_wave_barrier();
        }

        #pragma unroll
        for (int j = 0; j < 8; ++j)
            if (j < ne) atomicAdd(&acc[(size_t)d[j] * 64 + c], a[j]);
        e0 = en;
    }
}

// ---------------------------------------------------------------------------
// Cin=1 conv (baseline-verified): out[dst,:64] += s1[src] * W_up[k,0,:].
// ---------------------------------------------------------------------------
__global__ __launch_bounds__(256) void conv_up_kernel(
    const float* __restrict__ s1, const float* __restrict__ Wup,
    const int* __restrict__ gsrc, const int* __restrict__ sdst,
    float* __restrict__ out, int E)
{
    const int k = blockIdx.y;
    const int c = threadIdx.x & 63;
    const int w = threadIdx.x >> 6;
    const float wv = Wup[k * 64 + c];
    for (int e = blockIdx.x * 4 + w; e < E; e += gridDim.x * 4) {
        const float val = s1[gsrc[(size_t)k * E + e]];
        const int   di  = sdst[(size_t)k * E + e];
        atomicAdd(&out[(size_t)di * 64 + c], val * wv);
    }
}

// ---------------------------------------------------------------------------
// Cout=1 conv: acc1[dst] += dot(s[src,:64], W_sum[k,:,0]). Thread-per-edge.
// ---------------------------------------------------------------------------
__global__ __launch_bounds__(256) void conv_sum_kernel(
    const float* __restrict__ s, const float* __restrict__ Wsum,
    const int* __restrict__ src, const int* __restrict__ dst,
    float* __restrict__ acc1, int E)
{
    const int k = blockIdx.y;
    __shared__ float Wl[64];
    if (threadIdx.x < 64) Wl[threadIdx.x] = Wsum[k * 64 + threadIdx.x];
    __syncthreads();
    for (int e = blockIdx.x * 256 + threadIdx.x; e < E; e += gridDim.x * 256) {
        const int si = src[(size_t)k * E + e];
        const float4* row = (const float4*)(s + (size_t)si * 64);
        float acc = 0.f;
        #pragma unroll
        for (int q = 0; q < 16; ++q) {
            const float4 v = row[q];
            acc = fmaf(v.x, Wl[q * 4 + 0], acc);
            acc = fmaf(v.y, Wl[q * 4 + 1], acc);
            acc = fmaf(v.z, Wl[q * 4 + 2], acc);
            acc = fmaf(v.w, Wl[q * 4 + 3], acc);
        }
        atomicAdd(&acc1[dst[(size_t)k * E + e]], acc);
    }
}

// ---------------------------------------------------------------------------
// Per-channel (C=64) sum/sumsq (baseline-verified atomic form).
// ---------------------------------------------------------------------------
__global__ __launch_bounds__(256) void stats64(
    const float* __restrict__ x, int N, float* __restrict__ st)
{
    const int c  = threadIdx.x & 63;
    const int rg = threadIdx.x >> 6;
    float s = 0.f, q = 0.f;
    for (int r = blockIdx.x * 4 + rg; r < N; r += gridDim.x * 4) {
        const float v = x[(size_t)r * 64 + c];
        s += v;
        q = fmaf(v, v, q);
    }
    __shared__ float ls[256], lq[256];
    ls[threadIdx.x] = s; lq[threadIdx.x] = q;
    __syncthreads();
    if (threadIdx.x < 64) {
        s = ls[c] + ls[64 + c] + ls[128 + c] + ls[192 + c];
        q = lq[c] + lq[64 + c] + lq[128 + c] + lq[192 + c];
        atomicAdd(&st[c], s);
        atomicAdd(&st[64 + c], q);
    }
}

__global__ __launch_bounds__(256) void stats1(
    const float* __restrict__ x, int N, float* __restrict__ st)
{
    float s = 0.f, q = 0.f;
    for (int i = blockIdx.x * 256 + threadIdx.x; i < N; i += gridDim.x * 256) {
        const float v = x[i];
        s += v;
        q = fmaf(v, v, q);
    }
    __shared__ float ls[256], lq[256];
    ls[threadIdx.x] = s; lq[threadIdx.x] = q;
    __syncthreads();
    for (int off = 128; off > 0; off >>= 1) {
        if (threadIdx.x < off) {
            ls[threadIdx.x] += ls[threadIdx.x + off];
            lq[threadIdx.x] += lq[threadIdx.x + off];
        }
        __syncthreads();
    }
    if (threadIdx.x == 0) { atomicAdd(&st[0], ls[0]); atomicAdd(&st[1], lq[0]); }
}

// ---------------------------------------------------------------------------
// In-place BN + activation (ACT 0=LeakyReLU, 1=sigmoid), optional += add.
// ---------------------------------------------------------------------------
template<int ACT>
__global__ __launch_bounds__(256) void apply_bn(
    float* __restrict__ x, const float* __restrict__ st, int N, float invN,
    const float* __restrict__ gam, const float* __restrict__ bet,
    const float* __restrict__ add)
{
    __shared__ float sc[64], sh[64];
    if (threadIdx.x < 64) {
        const int c = threadIdx.x;
        const float m = st[c] * invN;
        const float v = st[64 + c] * invN - m * m;
        const float s = rsqrtf(v + EPS) * gam[c];
        sc[c] = s;
        sh[c] = bet[c] - m * s;
    }
    __syncthreads();
    const size_t n = (size_t)N * 64;
    for (size_t i = (size_t)blockIdx.x * 256 + threadIdx.x; i < n;
         i += (size_t)gridDim.x * 256) {
        const int c = (int)(i & 63);
        float y = fmaf(x[i], sc[c], sh[c]);
        if (ACT == 0) y = (y >= 0.f) ? y : SLOPE * y;
        else          y = 1.f / (1.f + __expf(-y));
        if (add) y += add[i];
        x[i] = y;
    }
}

__global__ __launch_bounds__(256) void apply_bn1(
    float* __restrict__ x, const float* __restrict__ st, int N, float invN,
    const float* __restrict__ gam, const float* __restrict__ bet)
{
    const float m  = st[0] * invN;
    const float v  = st[1] * invN - m * m;
    const float s  = rsqrtf(v + EPS) * gam[0];
    const float sh = bet[0] - m * s;
    for (int i = blockIdx.x * 256 + threadIdx.x; i < N; i += gridDim.x * 256) {
        const float y = fmaf(x[i], s, sh);
        x[i] = (y >= 0.f) ? y : SLOPE * y;
    }
}

// ---------------------------------------------------------------------------
extern "C" void kernel_launch(void* const* d_in, const int* in_sizes, int n_in,
                              void* d_out, int out_size, void* d_ws, size_t ws_size,
                              hipStream_t stream)
{
    const float* gate     = (const float*)d_in[0];
    const float* shortcut = (const float*)d_in[1];
    const int*   src_down = (const int*)d_in[2];
    const int*   dst_down = (const int*)d_in[3];
    const int*   src_g    = (const int*)d_in[4];
    const int*   dst_g    = (const int*)d_in[5];
    const float* W_sc     = (const float*)d_in[6];
    const float* W_g      = (const float*)d_in[8];
    const float* W_gu     = (const float*)d_in[10];
    const float* W_sum    = (const float*)d_in[12];
    const float* W_up     = (const float*)d_in[13];
    const float* gam_sc   = (const float*)d_in[15];
    const float* bet_sc   = (const float*)d_in[16];
    const float* gam_g    = (const float*)d_in[17];
    const float* bet_g    = (const float*)d_in[18];
    const float* gam_gu   = (const float*)d_in[19];
    const float* bet_gu   = (const float*)d_in[20];
    const float* gam_sum  = (const float*)d_in[21];
    const float* bet_sum  = (const float*)d_in[22];
    const float* gam_up   = (const float*)d_in[23];
    const float* bet_up   = (const float*)d_in[24];

    const int K   = 27;
    const int Nc  = in_sizes[0] / 128;   // 60000
    const int Nf  = in_sizes[1] / 64;    // 200000
    const int Ekd = in_sizes[2] / K;     // 40000
    const int Ekg = in_sizes[4] / K;     // 25000

    float* A  = (float*)d_ws;            // acc_theta -> theta
    float* B  = A + (size_t)Nc * 64;     // acc_phi   -> phi
    float* C  = B + (size_t)Nc * 64;     // acc_phi2  -> s
    float* D  = C + (size_t)Nc * 64;     // acc_s1    -> s1
    float* ST = D + Nc;                  // stats: 640 floats
    const size_t zeroBytes = ((size_t)Nc * 64 * 3 + (size_t)Nc + 640) * sizeof(float);
    hipMemsetAsync(d_ws, 0, zeroBytes, stream);
    hipMemsetAsync(d_out, 0, (size_t)out_size * sizeof(float), stream);
    float* out = (float*)d_out;

    const dim3 blk(256);

    // Grid sizing for whole residency rounds (no straggler round):
    //  CIN=64: 24 KB LDS -> 6 blocks/CU -> 1536 resident; 27*56 = 1512 <= 1536
    //  CIN=128: 40 KB LDS -> 4 blocks/CU -> 1024 resident; 27*75 = 2025 <= 2048
    // theta = leaky(bn(sconv(shortcut, W_sc, src_down->dst_down)))
    conv_scatter8<1><<<dim3(56, K), blk, 0, stream>>>(shortcut, W_sc, src_down, dst_down, A, Ekd);
    // phi_raw = sconv(gate, W_g, src_g->dst_g)
    conv_scatter8<2><<<dim3(75, K), blk, 0, stream>>>(gate, W_g, src_g, dst_g, B, Ekg);

    stats64<<<256, blk, 0, stream>>>(A, Nc, ST + 0);
    stats64<<<256, blk, 0, stream>>>(B, Nc, ST + 128);
    apply_bn<0><<<1024, blk, 0, stream>>>(A, ST + 0,   Nc, 1.0f / Nc, gam_sc, bet_sc, nullptr);
    apply_bn<0><<<1024, blk, 0, stream>>>(B, ST + 128, Nc, 1.0f / Nc, gam_g,  bet_g,  nullptr);

    // phi = leaky(bn(sconv(phi, W_gu, dst_g->src_g)))  (transposed index pairs)
    conv_scatter8<1><<<dim3(56, K), blk, 0, stream>>>(B, W_gu, dst_g, src_g, C, Ekg);
    stats64<<<256, blk, 0, stream>>>(C, Nc, ST + 256);
    // s = leaky(bn(C)) + theta
    apply_bn<0><<<1024, blk, 0, stream>>>(C, ST + 256, Nc, 1.0f / Nc, gam_gu, bet_gu, A);

    // s1 = leaky(bn(sconv(s, W_sum, src_g->dst_g)))   (Cout = 1)
    conv_sum_kernel<<<dim3(32, K), blk, 0, stream>>>(C, W_sum, src_g, dst_g, D, Ekg);
    stats1<<<256, blk, 0, stream>>>(D, Nc, ST + 384);
    apply_bn1<<<256, blk, 0, stream>>>(D, ST + 384, Nc, 1.0f / Nc, gam_sum, bet_sum);

    // out = sigmoid(bn(sconv(s1, W_up, dst_down->src_down)))  (Cin = 1, fine res)
    conv_up_kernel<<<dim3(64, K), blk, 0, stream>>>(D, W_up, dst_down, src_down, out, Ekd);
    stats64<<<512, blk, 0, stream>>>(out, Nf, ST + 512);
    apply_bn<1><<<2048, blk, 0, stream>>>(out, ST + 512, Nf, 1.0f / Nf, gam_up, bet_up, nullptr);
}